// Round 1
// baseline (30822.400 us; speedup 1.0000x reference)
//
#include <hip/hip_runtime.h>
#include <hip/hip_cooperative_groups.h>

namespace cg = cooperative_groups;

#define T_STEPS 512
#define H_DIM   2048
#define G_DIM   8192   // 4*H
#define NGUESS  4096

__device__ __forceinline__ float sigf(float x) { return 1.0f / (1.0f + expf(-x)); }

// ---------------------------------------------------------------------------
// Kernel 1: gather embeddings -> xs[T][2048]  (concat guess_embed, feedback_embed)
// ---------------------------------------------------------------------------
__global__ void embed_kernel(const int* __restrict__ guesses,
                             const int* __restrict__ feedbacks,
                             const float* __restrict__ gemb,
                             const float* __restrict__ femb,
                             float* __restrict__ xs) {
    int t = blockIdx.x;                      // 512 blocks
    int g = guesses[t];
    int f = feedbacks[t];
    const float4* gs = (const float4*)(gemb + (size_t)g * 1024);
    const float4* fs = (const float4*)(femb + (size_t)f * 1024);
    float4* xg = (float4*)(xs + (size_t)t * H_DIM);
    int tid = threadIdx.x;                   // 256 threads
    xg[tid]       = gs[tid];                 // first 1024 floats (256 float4)
    xg[256 + tid] = fs[tid];                 // next 1024 floats
}

// ---------------------------------------------------------------------------
// Kernel 2: GX[t][r] = dot(W_ih[r], xs[t]) + b_ih[r] + b_hh[r]
// Tiled fp32 GEMM: 64(t) x 64(r) tile, K-step 16, 256 threads, 4x4 per thread.
// ---------------------------------------------------------------------------
__global__ void gx_gemm(const float* __restrict__ xs,
                        const float* __restrict__ Wih,
                        const float* __restrict__ bih,
                        const float* __restrict__ bhh,
                        float* __restrict__ GX) {
    __shared__ float As[64][17];   // [t_local][k]
    __shared__ float Bs[64][17];   // [r_local][k]
    int r0 = blockIdx.x * 64;
    int t0 = blockIdx.y * 64;
    int tid = threadIdx.x;
    int tx = tid & 15;             // -> r
    int ty = tid >> 4;             // -> t
    int lr = tid >> 2;             // 0..63 load row
    int lk = (tid & 3) * 4;        // 0,4,8,12 load k
    float acc[4][4] = {};

    for (int k0 = 0; k0 < H_DIM; k0 += 16) {
        const float* xp = xs  + (size_t)(t0 + lr) * H_DIM + k0 + lk;
        const float* wp = Wih + (size_t)(r0 + lr) * H_DIM + k0 + lk;
        As[lr][lk + 0] = xp[0]; As[lr][lk + 1] = xp[1];
        As[lr][lk + 2] = xp[2]; As[lr][lk + 3] = xp[3];
        Bs[lr][lk + 0] = wp[0]; Bs[lr][lk + 1] = wp[1];
        Bs[lr][lk + 2] = wp[2]; Bs[lr][lk + 3] = wp[3];
        __syncthreads();
#pragma unroll
        for (int kk = 0; kk < 16; ++kk) {
            float a[4], b[4];
#pragma unroll
            for (int i = 0; i < 4; ++i) a[i] = As[ty * 4 + i][kk];
#pragma unroll
            for (int j = 0; j < 4; ++j) b[j] = Bs[tx * 4 + j][kk];
#pragma unroll
            for (int i = 0; i < 4; ++i)
#pragma unroll
                for (int j = 0; j < 4; ++j) acc[i][j] += a[i] * b[j];
        }
        __syncthreads();
    }
#pragma unroll
    for (int i = 0; i < 4; ++i)
#pragma unroll
        for (int j = 0; j < 4; ++j) {
            int t = t0 + ty * 4 + i;
            int r = r0 + tx * 4 + j;
            GX[(size_t)t * G_DIM + r] = acc[i][j] + bih[r] + bhh[r];
        }
}

// ---------------------------------------------------------------------------
// Kernel 3: cooperative sequential LSTM loop.
// 256 WGs x 256 threads. WG w owns units [w*8, w*8+8). Wave v computes gate
// block v (i/f/g/o) rows for those 8 units. One grid.sync per step.
// h double-buffered in global ws; agent-scope atomics for cross-XCD coherence.
// ---------------------------------------------------------------------------
__global__ void __launch_bounds__(256, 1)
lstm_loop(const float* __restrict__ Whh,
          const float* __restrict__ GX,
          const float* __restrict__ xs,
          float* __restrict__ hbuf) {
    cg::grid_group grid = cg::this_grid();
    __shared__ float h_lds[H_DIM];
    __shared__ float gates[32];

    const int wg   = blockIdx.x;        // 256
    const int base = wg * 8;            // unit base
    const int tid  = threadIdx.x;
    const int lane = tid & 63;
    const int wv   = tid >> 6;          // wave 0..3 == gate block

    for (int t = 0; t < T_STEPS; ++t) {
        const float* gx = GX + (size_t)t * G_DIM;
        if (t == 0) {
            // h == 0: gates are just GX[0]
            if (tid < 32) {
                int u = tid & 7, g = tid >> 3;
                gates[g * 8 + u] = gx[g * H_DIM + base + u];
            }
        } else {
            const float* h = hbuf + (size_t)(t & 1) * H_DIM;
            // stage h into LDS (agent-scope loads: cross-XCD coherent)
            for (int i = tid; i < H_DIM; i += 256)
                h_lds[i] = __hip_atomic_load(h + i, __ATOMIC_RELAXED,
                                             __HIP_MEMORY_SCOPE_AGENT);
            __syncthreads();
            const float4* hv = (const float4*)h_lds;
#pragma unroll 1
            for (int u = 0; u < 8; ++u) {
                int row = wv * H_DIM + base + u;
                const float4* wrow = (const float4*)(Whh + (size_t)row * H_DIM);
                float acc = 0.0f;
#pragma unroll
                for (int c = 0; c < 8; ++c) {
                    float4 w4 = wrow[c * 64 + lane];
                    float4 h4 = hv[c * 64 + lane];
                    acc += w4.x * h4.x + w4.y * h4.y + w4.z * h4.z + w4.w * h4.w;
                }
#pragma unroll
                for (int off = 32; off > 0; off >>= 1)
                    acc += __shfl_xor(acc, off, 64);
                if (lane == 0) gates[wv * 8 + u] = acc + gx[row];
            }
        }
        __syncthreads();
        if (tid < 8) {
            int u = tid;
            float gi = gates[0 * 8 + u];
            float gf = gates[1 * 8 + u];
            float gg = gates[2 * 8 + u];
            float go = gates[3 * 8 + u];
            float c_in = (t > 0) ? xs[(size_t)t * H_DIM + base + u] : 0.0f;
            float c  = sigf(gf) * c_in + sigf(gi) * tanhf(gg);
            float hn = sigf(go) * tanhf(c);
            __hip_atomic_store(hbuf + (size_t)((t + 1) & 1) * H_DIM + base + u,
                               hn, __ATOMIC_RELAXED, __HIP_MEMORY_SCOPE_AGENT);
        }
        __threadfence();
        grid.sync();
    }
}

// ---------------------------------------------------------------------------
// Kernel 4: logits[r] = dot(W_fc[r], h) + b_fc[r]
// ---------------------------------------------------------------------------
__global__ void fc_kernel(const float* __restrict__ Wfc,
                          const float* __restrict__ bfc,
                          const float* __restrict__ h,
                          float* __restrict__ logits) {
    int wg = blockIdx.x;           // 256
    int tid = threadIdx.x;
    int lane = tid & 63, wv = tid >> 6;
    int r0 = wg * 16;
    const float4* hv = (const float4*)h;
    for (int rr = wv; rr < 16; rr += 4) {
        int r = r0 + rr;
        const float4* wrow = (const float4*)(Wfc + (size_t)r * H_DIM);
        float acc = 0.0f;
#pragma unroll
        for (int c = 0; c < 8; ++c) {
            float4 w4 = wrow[c * 64 + lane];
            float4 h4 = hv[c * 64 + lane];
            acc += w4.x * h4.x + w4.y * h4.y + w4.z * h4.z + w4.w * h4.w;
        }
#pragma unroll
        for (int off = 32; off > 0; off >>= 1) acc += __shfl_xor(acc, off, 64);
        if (lane == 0) logits[r] = acc + bfc[r];
    }
}

// ---------------------------------------------------------------------------
// Kernel 5: softmax over 4096 logits -> out
// ---------------------------------------------------------------------------
__global__ void softmax_kernel(const float* __restrict__ logits,
                               float* __restrict__ out) {
    __shared__ float sm[8];
    int tid = threadIdx.x, lane = tid & 63, wv = tid >> 6;
    float m = -1e30f;
    for (int i = tid; i < NGUESS; i += 256) m = fmaxf(m, logits[i]);
#pragma unroll
    for (int off = 32; off > 0; off >>= 1) m = fmaxf(m, __shfl_xor(m, off, 64));
    if (lane == 0) sm[wv] = m;
    __syncthreads();
    m = fmaxf(fmaxf(sm[0], sm[1]), fmaxf(sm[2], sm[3]));
    float s = 0.0f;
    for (int i = tid; i < NGUESS; i += 256) s += expf(logits[i] - m);
#pragma unroll
    for (int off = 32; off > 0; off >>= 1) s += __shfl_xor(s, off, 64);
    if (lane == 0) sm[4 + wv] = s;
    __syncthreads();
    s = sm[4] + sm[5] + sm[6] + sm[7];
    float inv = 1.0f / s;
    for (int i = tid; i < NGUESS; i += 256) out[i] = expf(logits[i] - m) * inv;
}

// ---------------------------------------------------------------------------
extern "C" void kernel_launch(void* const* d_in, const int* in_sizes, int n_in,
                              void* d_out, int out_size, void* d_ws, size_t ws_size,
                              hipStream_t stream) {
    const int*   guesses   = (const int*)d_in[0];
    const int*   feedbacks = (const int*)d_in[1];
    const float* gemb      = (const float*)d_in[2];
    const float* femb      = (const float*)d_in[3];
    const float* Wih       = (const float*)d_in[4];
    const float* Whh       = (const float*)d_in[5];
    const float* bih       = (const float*)d_in[6];
    const float* bhh       = (const float*)d_in[7];
    const float* Wfc       = (const float*)d_in[8];
    const float* bfc       = (const float*)d_in[9];

    float* ws     = (float*)d_ws;
    float* xs     = ws;                              // 512*2048   = 1,048,576 f
    float* GX     = xs + (size_t)T_STEPS * H_DIM;    // 512*8192   = 4,194,304 f
    float* hbuf   = GX + (size_t)T_STEPS * G_DIM;    // 2*2048     = 4,096 f
    float* logits = hbuf + 2 * H_DIM;                // 4,096 f
    float* out    = (float*)d_out;

    embed_kernel<<<T_STEPS, 256, 0, stream>>>(guesses, feedbacks, gemb, femb, xs);

    dim3 g2(G_DIM / 64, T_STEPS / 64);               // 128 x 8
    gx_gemm<<<g2, 256, 0, stream>>>(xs, Wih, bih, bhh, GX);

    {
        void* args[] = { (void*)&Whh, (void*)&GX, (void*)&xs, (void*)&hbuf };
        hipLaunchCooperativeKernel((const void*)lstm_loop, dim3(256), dim3(256),
                                   args, 0, stream);
    }

    // final h is at parity (T_STEPS & 1) == 0
    fc_kernel<<<NGUESS / 16, 256, 0, stream>>>(Wfc, bfc, hbuf, logits);
    softmax_kernel<<<1, 256, 0, stream>>>(logits, out);
}